// Round 17
// baseline (71.983 us; speedup 1.0000x reference)
//
#include <hip/hip_runtime.h>
#include <hip/hip_bf16.h>

// QuantumFeedForward, fully fused:
//   q[n,w] = prod_{v in M_w} cos(theta_v)*cos(x[n,v])   (analytic circuit collapse)
//   out    = relu(q@W1^T+b1) @ W2^T + b2
// 32x32x16 MFMA. H^T = mfma(W1aug-frag, qaug-frag) -> pk-relu -> v_cvt_pk_bf16_f32
// (RNE) -> v_permlane32_swap -> GEMM A-quads in registers (verified R9-R16).
// R17: R14 chassis (best, 50.5us) with the wave RE-SHAPED to 64tok x 32col
// (i=2, j=1): 4 waves = 2M x 2N. Only decomposition changes: bg reads/wave/kt
// 8 -> 4, mfma:ds_read ratio 1:1 -> 2:1 (HGEN doubles to 4 mfma/kt, accepted).
// Per-CU LDS reads/kt 160 -> 96. Grid/LDS/staging/sync identical to R14.
// 256-thread blocks, BM=128 x BN=64, grid 1024 = 4 blocks/CU, no setprio,
// in-iteration HGEN (R16 pipeline reverted: measured neutral + scratch).

typedef __attribute__((ext_vector_type(8))) short bf16x8;
typedef __attribute__((ext_vector_type(16))) float f32x16;
typedef __attribute__((ext_vector_type(8))) unsigned short us8;
typedef unsigned int u32;

#define NTOK  16384
#define EMBED 512
#define FFN   2048
#define NQ    10
#define BM    128
#define BN    64
#define NKT   32          // K-tiles of 64 k

__device__ __forceinline__ unsigned short f2bf(float f) {
  union { float f; unsigned int u; } a; a.f = f;
  unsigned int r = a.u + 0x7FFFu + ((a.u >> 16) & 1u);   // RNE
  return (unsigned short)(r >> 16);
}

__device__ __forceinline__ void gload_lds16(const void* g, void* l) {
  __builtin_amdgcn_global_load_lds(
      (const __attribute__((address_space(1))) unsigned int*)g,
      (__attribute__((address_space(3))) unsigned int*)l, 16, 0, 0);
}

// ---------------- K0: fused prep (W2f + Qf + W1f), one launch ----------------
// W2f[((tile*128+kb)*64+l)*8+e] = W2[col=tile*32+(l&31)][k=kb*16+(l>>5)*8+e]
// Qf [(tile*64+l)*8+e]          = qaug[wire=(l>>5)*8+e][token=tile*32+(l&31)]
// W1f[(blk*64+l)*8+e]           = W1aug[wire=(l>>5)*8+e][k=blk*32+(l&31)]
__global__ __launch_bounds__(256) void k_prep(const float* __restrict__ x,
                                              const float* __restrict__ theta,
                                              const float* __restrict__ W1,
                                              const float* __restrict__ b1,
                                              const float* __restrict__ W2,
                                              unsigned short* __restrict__ W2f,
                                              unsigned short* __restrict__ W1f,
                                              unsigned short* __restrict__ Qf) {
  int bb = blockIdx.x;
  if (bb < 512) {                       // ---- W2f: 131072 chunks ----
    int gid = bb * 256 + threadIdx.x;
    int l = gid & 63, kb = (gid >> 6) & 127, tile = gid >> 13;
    int col = tile * 32 + (l & 31);
    int k0 = kb * 16 + (l >> 5) * 8;
    const float* src = W2 + (size_t)col * FFN + k0;
    float4 v0 = *(const float4*)src;
    float4 v1 = *(const float4*)(src + 4);
    us8 o;
    o[0] = f2bf(v0.x); o[1] = f2bf(v0.y); o[2] = f2bf(v0.z); o[3] = f2bf(v0.w);
    o[4] = f2bf(v1.x); o[5] = f2bf(v1.y); o[6] = f2bf(v1.z); o[7] = f2bf(v1.w);
    *(us8*)(W2f + (size_t)gid * 8) = o;
  } else if (bb < 640) {                // ---- Qf: 32768 chunks ----
    int gid = (bb - 512) * 256 + threadIdx.x;
    int l = gid & 63, tile = gid >> 6;
    int tok = tile * 32 + (l & 31), g = l >> 5;
    const int masks[NQ] = {0x2AB,0x3FD,0x3FA,0x3F5,0x3EA,0x3D5,0x3AA,0x355,0x2AA,0x155};
    float z[NQ], qv[NQ];
#pragma unroll
    for (int w = 0; w < NQ; ++w)
      z[w] = __builtin_cosf(x[(size_t)tok * EMBED + w]) * __builtin_cosf(theta[w]);
#pragma unroll
    for (int w = 0; w < NQ; ++w) {
      float p = 1.f;
#pragma unroll
      for (int v = 0; v < NQ; ++v)
        if ((masks[w] >> v) & 1) p *= z[v];
      qv[w] = p;
    }
    us8 o = (us8)0;
    if (g == 0) {
#pragma unroll
      for (int e = 0; e < 8; ++e) o[e] = f2bf(qv[e]);
    } else {
      o[0] = f2bf(qv[8]); o[1] = f2bf(qv[9]); o[2] = f2bf(1.f);
    }
    *(us8*)(Qf + (size_t)gid * 8) = o;
  } else {                              // ---- W1f: 4096 chunks ----
    int gid = (bb - 640) * 256 + threadIdx.x;
    int l = gid & 63, blk = gid >> 6;
    int k = blk * 32 + (l & 31);
    int wg = (l >> 5) * 8;
    us8 o;
#pragma unroll
    for (int e = 0; e < 8; ++e) {
      int wire = wg + e;
      float v = (wire < NQ) ? W1[k * NQ + wire] : (wire == NQ ? b1[k] : 0.f);
      o[e] = f2bf(v);
    }
    *(us8*)(W1f + (size_t)gid * 8) = o;
  }
}

// ---------------- K1: fused H-gen + GEMM, 4 blocks/CU, 2Mx2N waves ----------------
__global__ __launch_bounds__(256, 4) void k_fused(const unsigned short* __restrict__ Qf,
                                                  const unsigned short* __restrict__ W1f,
                                                  const unsigned short* __restrict__ W2f,
                                                  const float* __restrict__ b2,
                                                  float* __restrict__ out) {
  __shared__ short Bw[2][8 * 64 * 8];    // 2 x 8KB: [tile2*4+kb][lane][8], frag order
  __shared__ short W1s[2][2 * 64 * 8];   // 2 x 2KB: [b][lane][8]

  // XCD-aware bijective swizzle: 1024 blocks, 128 consecutive per XCD; n fastest.
  int bid = blockIdx.x;
  int swz = (bid & 7) * 128 + (bid >> 3);
  const int m0 = (swz >> 3) * BM;      // 128 m-tiles
  const int n0 = (swz & 7) * BN;       // 8 n-tiles
  const int tid  = threadIdx.x;
  const int lane = tid & 63;
  const int wave = tid >> 6;           // 4 waves: 2M x 2N, each 64 tok x 32 cols
  const int wm = wave >> 1, wn = wave & 1;
  const int h = lane >> 5, t31 = lane & 31;
  const int nt0 = n0 >> 5;             // global col-tile base (2 tiles of 32)

  // q_aug B-frags for this wave's 2 token groups of 32 (register-resident)
  bf16x8 qf0 = *(const bf16x8*)&Qf[(((size_t)(m0 >> 5) + wm * 2 + 0) * 64 + lane) * 8];
  bf16x8 qf1 = *(const bf16x8*)&Qf[(((size_t)(m0 >> 5) + wm * 2 + 1) * 64 + lane) * 8];

  f32x16 acc[2] = {};                  // acc[i]: token group i, this wave's 32 cols

  // Stage one 64-k tile: 512 Bw chunks (2/thread) + 128 W1 chunks.
#define STAGE(KT, B)                                                            \
  { _Pragma("unroll")                                                           \
    for (int hf = 0; hf < 2; ++hf) {                                            \
      int ch = hf * 256 + tid;                                                  \
      int tile2 = ch >> 8, kb = (ch >> 6) & 3, ln = ch & 63;                    \
      gload_lds16(&W2f[(((size_t)(nt0 + tile2) * 128 + (KT) * 4 + kb) * 64 + ln) * 8], \
                  &Bw[B][ch * 8]);                                              \
    }                                                                           \
    if (tid < 128)                                                              \
      gload_lds16(&W1f[(((size_t)(KT) * 2 + (tid >> 6)) * 64 + (tid & 63)) * 8],\
                  &W1s[B][tid * 8]); }

  // H^T = mfma(W1aug, qaug); pk-relu; RNE cvt_pk; permlane32_swap -> two A-quads
#define HGEN1(WF, QF, AQ0, AQ1)                                                 \
  { f32x16 zz = {};                                                             \
    f32x16 d = __builtin_amdgcn_mfma_f32_32x32x16_bf16((WF), (QF), zz, 0, 0, 0); \
    d = __builtin_elementwise_max(d, zz);                                       \
    u32 w0, w1, w2, w3, w4, w5, w6, w7;                                         \
    asm("v_cvt_pk_bf16_f32 %0, %1, %2":"=v"(w0):"v"(d[0]),"v"(d[1]));           \
    asm("v_cvt_pk_bf16_f32 %0, %1, %2":"=v"(w1):"v"(d[2]),"v"(d[3]));           \
    asm("v_cvt_pk_bf16_f32 %0, %1, %2":"=v"(w2):"v"(d[4]),"v"(d[5]));           \
    asm("v_cvt_pk_bf16_f32 %0, %1, %2":"=v"(w3):"v"(d[6]),"v"(d[7]));           \
    asm("v_cvt_pk_bf16_f32 %0, %1, %2":"=v"(w4):"v"(d[8]),"v"(d[9]));           \
    asm("v_cvt_pk_bf16_f32 %0, %1, %2":"=v"(w5):"v"(d[10]),"v"(d[11]));         \
    asm("v_cvt_pk_bf16_f32 %0, %1, %2":"=v"(w6):"v"(d[12]),"v"(d[13]));         \
    asm("v_cvt_pk_bf16_f32 %0, %1, %2":"=v"(w7):"v"(d[14]),"v"(d[15]));         \
    asm("v_permlane32_swap_b32 %0, %1" : "+v"(w0), "+v"(w2));                   \
    asm("v_permlane32_swap_b32 %0, %1" : "+v"(w1), "+v"(w3));                   \
    asm("v_permlane32_swap_b32 %0, %1" : "+v"(w4), "+v"(w6));                   \
    asm("v_permlane32_swap_b32 %0, %1" : "+v"(w5), "+v"(w7));                   \
    union { u32 u[4]; bf16x8 v; } u0, u1;                                       \
    u0.u[0]=w0; u0.u[1]=w1; u0.u[2]=w2; u0.u[3]=w3;                             \
    u1.u[0]=w4; u1.u[1]=w5; u1.u[2]=w6; u1.u[3]=w7;                             \
    AQ0 = u0.v; AQ1 = u1.v; }

  // ---- prologue: stage tile 0 ----
  STAGE(0, 0);

  // ---- main loop: one 64-k tile per iteration ----
  for (int kt = 0; kt < NKT; ++kt) {
    const int cur = kt & 1;
    asm volatile("s_waitcnt vmcnt(0)" ::: "memory");   // stage(kt) landed
    __builtin_amdgcn_s_barrier();                      // buf cur^1 reads done
    asm volatile("" ::: "memory");
    if (kt + 1 < NKT) STAGE(kt + 1, cur ^ 1);          // post-barrier: race-safe

    // W1 frags + HGEN -> A-quads: a[i][s], i = token group, s = 16-k sub-block
    bf16x8 wf0 = *(const bf16x8*)&W1s[cur][(0 * 64 + lane) * 8];
    bf16x8 wf1 = *(const bf16x8*)&W1s[cur][(1 * 64 + lane) * 8];
    bf16x8 a00, a01, a02, a03, a10, a11, a12, a13;
    HGEN1(wf0, qf0, a00, a01);
    HGEN1(wf1, qf0, a02, a03);
    HGEN1(wf0, qf1, a10, a11);
    HGEN1(wf1, qf1, a12, a13);

    // GEMM: this wave's 32 cols (tile2 = wn), 4 bg reads feed 8 mfma (2:1)
    bf16x8 bg0 = *(const bf16x8*)&Bw[cur][((wn * 4 + 0) * 64 + lane) * 8];
    bf16x8 bg1 = *(const bf16x8*)&Bw[cur][((wn * 4 + 1) * 64 + lane) * 8];
    bf16x8 bg2 = *(const bf16x8*)&Bw[cur][((wn * 4 + 2) * 64 + lane) * 8];
    bf16x8 bg3 = *(const bf16x8*)&Bw[cur][((wn * 4 + 3) * 64 + lane) * 8];
    acc[0] = __builtin_amdgcn_mfma_f32_32x32x16_bf16(a00, bg0, acc[0], 0, 0, 0);
    acc[1] = __builtin_amdgcn_mfma_f32_32x32x16_bf16(a10, bg0, acc[1], 0, 0, 0);
    acc[0] = __builtin_amdgcn_mfma_f32_32x32x16_bf16(a01, bg1, acc[0], 0, 0, 0);
    acc[1] = __builtin_amdgcn_mfma_f32_32x32x16_bf16(a11, bg1, acc[1], 0, 0, 0);
    acc[0] = __builtin_amdgcn_mfma_f32_32x32x16_bf16(a02, bg2, acc[0], 0, 0, 0);
    acc[1] = __builtin_amdgcn_mfma_f32_32x32x16_bf16(a12, bg2, acc[1], 0, 0, 0);
    acc[0] = __builtin_amdgcn_mfma_f32_32x32x16_bf16(a03, bg3, acc[0], 0, 0, 0);
    acc[1] = __builtin_amdgcn_mfma_f32_32x32x16_bf16(a13, bg3, acc[1], 0, 0, 0);
  }

  // ---- epilogue: out = acc + b2 ----
  {
    const int col = n0 + wn * 32 + t31;
    const float bbv = b2[col];
#pragma unroll
    for (int i = 0; i < 2; ++i) {
#pragma unroll
      for (int r = 0; r < 16; ++r) {
        int tok = m0 + wm * 64 + i * 32 + (r & 3) + 8 * (r >> 2) + 4 * h;
        out[(size_t)tok * EMBED + col] = acc[i][r] + bbv;
      }
    }
  }
#undef STAGE
#undef HGEN1
}

extern "C" void kernel_launch(void* const* d_in, const int* in_sizes, int n_in,
                              void* d_out, int out_size, void* d_ws, size_t ws_size,
                              hipStream_t stream) {
  const float* x     = (const float*)d_in[0];
  const float* theta = (const float*)d_in[1];
  const float* W1    = (const float*)d_in[2];
  const float* b1    = (const float*)d_in[3];
  const float* W2    = (const float*)d_in[4];
  const float* b2    = (const float*)d_in[5];
  float* out = (float*)d_out;

  char* ws = (char*)d_ws;
  unsigned short* W2f = (unsigned short*)ws;                          // 2 MB
  unsigned short* W1f = (unsigned short*)(ws + (2u << 20));           // 64 KB
  unsigned short* Qfg = (unsigned short*)(ws + (2u << 20) + (64u << 10)); // 512 KB

  k_prep <<<656, 256, 0, stream>>>(x, theta, W1, b1, W2, W2f, W1f, Qfg);
  k_fused<<<(NTOK / BM) * (EMBED / BN), 256, 0, stream>>>(Qfg, W1f, W2f, b2, out);
}

// Round 18
// 55.655 us; speedup vs baseline: 1.2934x; 1.2934x over previous
//
#include <hip/hip_runtime.h>
#include <hip/hip_bf16.h>

// QuantumFeedForward, fully fused (R14 configuration — best measured: 50.5us
// kernel, 55.7us total):
//   q[n,w] = prod_{v in M_w} cos(theta_v)*cos(x[n,v])   (analytic circuit collapse)
//   out    = relu(q@W1^T+b1) @ W2^T + b2
// 32x32x16 MFMA. H^T = mfma(W1aug-frag, qaug-frag) -> pk-relu -> v_cvt_pk_bf16_f32
// (RNE) -> v_permlane32_swap -> GEMM A-quads in registers (verified R9-R16).
// 256-thread blocks (4 waves, 32x64 wave tiles), BM=128 x BN=64, grid 1024 =
// 4 independent blocks/CU (small barrier domains). No setprio (m190). GEMM
// j-chains interleaved. W2 B-frags LDS-staged in fragment order (linear =
// gload_lds-legal and conflict-free ds_read); one vmcnt(0)+s_barrier per kt.

typedef __attribute__((ext_vector_type(8))) short bf16x8;
typedef __attribute__((ext_vector_type(16))) float f32x16;
typedef __attribute__((ext_vector_type(8))) unsigned short us8;
typedef unsigned int u32;

#define NTOK  16384
#define EMBED 512
#define FFN   2048
#define NQ    10
#define BM    128
#define BN    64
#define NKT   32          // K-tiles of 64 k

__device__ __forceinline__ unsigned short f2bf(float f) {
  union { float f; unsigned int u; } a; a.f = f;
  unsigned int r = a.u + 0x7FFFu + ((a.u >> 16) & 1u);   // RNE
  return (unsigned short)(r >> 16);
}

__device__ __forceinline__ void gload_lds16(const void* g, void* l) {
  __builtin_amdgcn_global_load_lds(
      (const __attribute__((address_space(1))) unsigned int*)g,
      (__attribute__((address_space(3))) unsigned int*)l, 16, 0, 0);
}

// ---------------- K0: fused prep (W2f + Qf + W1f), one launch ----------------
// W2f[((tile*128+kb)*64+l)*8+e] = W2[col=tile*32+(l&31)][k=kb*16+(l>>5)*8+e]
// Qf [(tile*64+l)*8+e]          = qaug[wire=(l>>5)*8+e][token=tile*32+(l&31)]
// W1f[(blk*64+l)*8+e]           = W1aug[wire=(l>>5)*8+e][k=blk*32+(l&31)]
__global__ __launch_bounds__(256) void k_prep(const float* __restrict__ x,
                                              const float* __restrict__ theta,
                                              const float* __restrict__ W1,
                                              const float* __restrict__ b1,
                                              const float* __restrict__ W2,
                                              unsigned short* __restrict__ W2f,
                                              unsigned short* __restrict__ W1f,
                                              unsigned short* __restrict__ Qf) {
  int bb = blockIdx.x;
  if (bb < 512) {                       // ---- W2f: 131072 chunks ----
    int gid = bb * 256 + threadIdx.x;
    int l = gid & 63, kb = (gid >> 6) & 127, tile = gid >> 13;
    int col = tile * 32 + (l & 31);
    int k0 = kb * 16 + (l >> 5) * 8;
    const float* src = W2 + (size_t)col * FFN + k0;
    float4 v0 = *(const float4*)src;
    float4 v1 = *(const float4*)(src + 4);
    us8 o;
    o[0] = f2bf(v0.x); o[1] = f2bf(v0.y); o[2] = f2bf(v0.z); o[3] = f2bf(v0.w);
    o[4] = f2bf(v1.x); o[5] = f2bf(v1.y); o[6] = f2bf(v1.z); o[7] = f2bf(v1.w);
    *(us8*)(W2f + (size_t)gid * 8) = o;
  } else if (bb < 640) {                // ---- Qf: 32768 chunks ----
    int gid = (bb - 512) * 256 + threadIdx.x;
    int l = gid & 63, tile = gid >> 6;
    int tok = tile * 32 + (l & 31), g = l >> 5;
    const int masks[NQ] = {0x2AB,0x3FD,0x3FA,0x3F5,0x3EA,0x3D5,0x3AA,0x355,0x2AA,0x155};
    float z[NQ], qv[NQ];
#pragma unroll
    for (int w = 0; w < NQ; ++w)
      z[w] = __builtin_cosf(x[(size_t)tok * EMBED + w]) * __builtin_cosf(theta[w]);
#pragma unroll
    for (int w = 0; w < NQ; ++w) {
      float p = 1.f;
#pragma unroll
      for (int v = 0; v < NQ; ++v)
        if ((masks[w] >> v) & 1) p *= z[v];
      qv[w] = p;
    }
    us8 o = (us8)0;
    if (g == 0) {
#pragma unroll
      for (int e = 0; e < 8; ++e) o[e] = f2bf(qv[e]);
    } else {
      o[0] = f2bf(qv[8]); o[1] = f2bf(qv[9]); o[2] = f2bf(1.f);
    }
    *(us8*)(Qf + (size_t)gid * 8) = o;
  } else {                              // ---- W1f: 4096 chunks ----
    int gid = (bb - 640) * 256 + threadIdx.x;
    int l = gid & 63, blk = gid >> 6;
    int k = blk * 32 + (l & 31);
    int wg = (l >> 5) * 8;
    us8 o;
#pragma unroll
    for (int e = 0; e < 8; ++e) {
      int wire = wg + e;
      float v = (wire < NQ) ? W1[k * NQ + wire] : (wire == NQ ? b1[k] : 0.f);
      o[e] = f2bf(v);
    }
    *(us8*)(W1f + (size_t)gid * 8) = o;
  }
}

// ---------------- K1: fused H-gen + GEMM, 4 blocks/CU ----------------
__global__ __launch_bounds__(256, 4) void k_fused(const unsigned short* __restrict__ Qf,
                                                  const unsigned short* __restrict__ W1f,
                                                  const unsigned short* __restrict__ W2f,
                                                  const float* __restrict__ b2,
                                                  float* __restrict__ out) {
  __shared__ short Bw[2][8 * 64 * 8];    // 2 x 8KB: [tile2*4+kb][lane][8], frag order
  __shared__ short W1s[2][2 * 64 * 8];   // 2 x 2KB: [b][lane][8]

  // XCD-aware bijective swizzle: 1024 blocks, 128 consecutive per XCD; n fastest.
  int bid = blockIdx.x;
  int swz = (bid & 7) * 128 + (bid >> 3);
  const int m0 = (swz >> 3) * BM;      // 128 m-tiles
  const int n0 = (swz & 7) * BN;       // 8 n-tiles
  const int tid  = threadIdx.x;
  const int lane = tid & 63;
  const int wave = tid >> 6;           // 4 waves, each 32 tok x 64 cols
  const int h = lane >> 5, t31 = lane & 31;
  const int nt0 = n0 >> 5;             // global col-tile base (2 tiles of 32)

  // q_aug B-frag for this wave's 32 tokens (single load, register-resident)
  bf16x8 qf = *(const bf16x8*)&Qf[(((size_t)(m0 >> 5) + wave) * 64 + lane) * 8];

  f32x16 acc[2] = {};

  // Stage one 64-k tile: 512 Bw chunks (2/thread) + 128 W1 chunks.
#define STAGE(KT, B)                                                            \
  { _Pragma("unroll")                                                           \
    for (int hf = 0; hf < 2; ++hf) {                                            \
      int ch = hf * 256 + tid;                                                  \
      int tile2 = ch >> 8, kb = (ch >> 6) & 3, ln = ch & 63;                    \
      gload_lds16(&W2f[(((size_t)(nt0 + tile2) * 128 + (KT) * 4 + kb) * 64 + ln) * 8], \
                  &Bw[B][ch * 8]);                                              \
    }                                                                           \
    if (tid < 128)                                                              \
      gload_lds16(&W1f[(((size_t)(KT) * 2 + (tid >> 6)) * 64 + (tid & 63)) * 8],\
                  &W1s[B][tid * 8]); }

  // H^T = mfma(W1aug, qaug); pk-relu; RNE cvt_pk; permlane32_swap -> A-quads
#define HGEN1(WF, AQ0, AQ1)                                                     \
  { f32x16 zz = {};                                                             \
    f32x16 d = __builtin_amdgcn_mfma_f32_32x32x16_bf16((WF), qf, zz, 0, 0, 0);  \
    d = __builtin_elementwise_max(d, zz);                                       \
    u32 dw0, dw1, dw2, dw3, dw4, dw5, dw6, dw7;                                 \
    asm("v_cvt_pk_bf16_f32 %0, %1, %2":"=v"(dw0):"v"(d[0]),"v"(d[1]));          \
    asm("v_cvt_pk_bf16_f32 %0, %1, %2":"=v"(dw1):"v"(d[2]),"v"(d[3]));          \
    asm("v_cvt_pk_bf16_f32 %0, %1, %2":"=v"(dw2):"v"(d[4]),"v"(d[5]));          \
    asm("v_cvt_pk_bf16_f32 %0, %1, %2":"=v"(dw3):"v"(d[6]),"v"(d[7]));          \
    asm("v_cvt_pk_bf16_f32 %0, %1, %2":"=v"(dw4):"v"(d[8]),"v"(d[9]));          \
    asm("v_cvt_pk_bf16_f32 %0, %1, %2":"=v"(dw5):"v"(d[10]),"v"(d[11]));        \
    asm("v_cvt_pk_bf16_f32 %0, %1, %2":"=v"(dw6):"v"(d[12]),"v"(d[13]));        \
    asm("v_cvt_pk_bf16_f32 %0, %1, %2":"=v"(dw7):"v"(d[14]),"v"(d[15]));        \
    asm("v_permlane32_swap_b32 %0, %1" : "+v"(dw0), "+v"(dw2));                 \
    asm("v_permlane32_swap_b32 %0, %1" : "+v"(dw1), "+v"(dw3));                 \
    asm("v_permlane32_swap_b32 %0, %1" : "+v"(dw4), "+v"(dw6));                 \
    asm("v_permlane32_swap_b32 %0, %1" : "+v"(dw5), "+v"(dw7));                 \
    union { u32 u[4]; bf16x8 v; } u0, u1;                                       \
    u0.u[0]=dw0; u0.u[1]=dw1; u0.u[2]=dw2; u0.u[3]=dw3;                         \
    u1.u[0]=dw4; u1.u[1]=dw5; u1.u[2]=dw6; u1.u[3]=dw7;                         \
    AQ0 = u0.v; AQ1 = u1.v; }

  // ---- prologue: stage tile 0 ----
  STAGE(0, 0);

  // ---- main loop: one 64-k tile per iteration ----
  for (int kt = 0; kt < NKT; ++kt) {
    const int cur = kt & 1;
    asm volatile("s_waitcnt vmcnt(0)" ::: "memory");   // stage(kt) landed
    __builtin_amdgcn_s_barrier();                      // 4-wave group: buf cur^1 free
    asm volatile("" ::: "memory");
    if (kt + 1 < NKT) STAGE(kt + 1, cur ^ 1);          // post-barrier: race-safe

    // W1 frags + HGEN -> A-quads (aq[s], s = kb-local 0..3)
    bf16x8 wf0 = *(const bf16x8*)&W1s[cur][(0 * 64 + lane) * 8];
    bf16x8 wf1 = *(const bf16x8*)&W1s[cur][(1 * 64 + lane) * 8];
    bf16x8 aq0, aq1, aq2, aq3;
    HGEN1(wf0, aq0, aq1);
    HGEN1(wf1, aq2, aq3);

    // GEMM: 8 mfma, j-chains interleaved (acc[0]/acc[1] alternate at issue)
    bf16x8 bg00 = *(const bf16x8*)&Bw[cur][((0 * 4 + 0) * 64 + lane) * 8];
    bf16x8 bg01 = *(const bf16x8*)&Bw[cur][((0 * 4 + 1) * 64 + lane) * 8];
    bf16x8 bg02 = *(const bf16x8*)&Bw[cur][((0 * 4 + 2) * 64 + lane) * 8];
    bf16x8 bg03 = *(const bf16x8*)&Bw[cur][((0 * 4 + 3) * 64 + lane) * 8];
    bf16x8 bg10 = *(const bf16x8*)&Bw[cur][((1 * 4 + 0) * 64 + lane) * 8];
    bf16x8 bg11 = *(const bf16x8*)&Bw[cur][((1 * 4 + 1) * 64 + lane) * 8];
    bf16x8 bg12 = *(const bf16x8*)&Bw[cur][((1 * 4 + 2) * 64 + lane) * 8];
    bf16x8 bg13 = *(const bf16x8*)&Bw[cur][((1 * 4 + 3) * 64 + lane) * 8];
    acc[0] = __builtin_amdgcn_mfma_f32_32x32x16_bf16(aq0, bg00, acc[0], 0, 0, 0);
    acc[1] = __builtin_amdgcn_mfma_f32_32x32x16_bf16(aq0, bg10, acc[1], 0, 0, 0);
    acc[0] = __builtin_amdgcn_mfma_f32_32x32x16_bf16(aq1, bg01, acc[0], 0, 0, 0);
    acc[1] = __builtin_amdgcn_mfma_f32_32x32x16_bf16(aq1, bg11, acc[1], 0, 0, 0);
    acc[0] = __builtin_amdgcn_mfma_f32_32x32x16_bf16(aq2, bg02, acc[0], 0, 0, 0);
    acc[1] = __builtin_amdgcn_mfma_f32_32x32x16_bf16(aq2, bg12, acc[1], 0, 0, 0);
    acc[0] = __builtin_amdgcn_mfma_f32_32x32x16_bf16(aq3, bg03, acc[0], 0, 0, 0);
    acc[1] = __builtin_amdgcn_mfma_f32_32x32x16_bf16(aq3, bg13, acc[1], 0, 0, 0);
  }

  // ---- epilogue: out = acc + b2 ----
#pragma unroll
  for (int j = 0; j < 2; ++j) {
    const int col = n0 + j * 32 + t31;
    const float bbv = b2[col];
#pragma unroll
    for (int r = 0; r < 16; ++r) {
      int tok = m0 + wave * 32 + (r & 3) + 8 * (r >> 2) + 4 * h;
      out[(size_t)tok * EMBED + col] = acc[j][r] + bbv;
    }
  }
#undef STAGE
#undef HGEN1
}

extern "C" void kernel_launch(void* const* d_in, const int* in_sizes, int n_in,
                              void* d_out, int out_size, void* d_ws, size_t ws_size,
                              hipStream_t stream) {
  const float* x     = (const float*)d_in[0];
  const float* theta = (const float*)d_in[1];
  const float* W1    = (const float*)d_in[2];
  const float* b1    = (const float*)d_in[3];
  const float* W2    = (const float*)d_in[4];
  const float* b2    = (const float*)d_in[5];
  float* out = (float*)d_out;

  char* ws = (char*)d_ws;
  unsigned short* W2f = (unsigned short*)ws;                          // 2 MB
  unsigned short* W1f = (unsigned short*)(ws + (2u << 20));           // 64 KB
  unsigned short* Qfg = (unsigned short*)(ws + (2u << 20) + (64u << 10)); // 512 KB

  k_prep <<<656, 256, 0, stream>>>(x, theta, W1, b1, W2, W2f, W1f, Qfg);
  k_fused<<<(NTOK / BM) * (EMBED / BN), 256, 0, stream>>>(Qfg, W1f, W2f, b2, out);
}